// Round 1
// baseline (724.902 us; speedup 1.0000x reference)
//
#include <hip/hip_runtime.h>
#include <stdint.h>

#define TOK 65536
#define DMODEL 768

typedef short  s16x8 __attribute__((ext_vector_type(8)));
typedef __bf16 bf16x8 __attribute__((ext_vector_type(8)));
typedef float  f32x4 __attribute__((ext_vector_type(4)));

__device__ __forceinline__ float b2f(unsigned short u) {
  union { unsigned int i; float f; } v; v.i = ((unsigned int)u) << 16; return v.f;
}
__device__ __forceinline__ unsigned short f2b(float f) {
  union { float f; unsigned int i; } v; v.f = f;
  unsigned int r = v.i + 0x7fffu + ((v.i >> 16) & 1u);
  return (unsigned short)(r >> 16);
}
__device__ __forceinline__ float wsum(float v) {
#pragma unroll
  for (int off = 32; off >= 1; off >>= 1) v += __shfl_xor(v, off, 64);
  return v;
}

// ---------------- GEMM: C[M,N] = A[M,K](bf16) @ W[N,K](bf16)^T (+bias) ----------------
// 128x128 tile, BK=64, 4 waves (2x2), each wave 64x64 via 4x4 mfma_f32_16x16x32_bf16.
template <bool BF16_OUT, bool HAS_BIAS>
__global__ void gemm_bt(const unsigned short* __restrict__ A,
                        const unsigned short* __restrict__ W,
                        void* __restrict__ Cv,
                        const float* __restrict__ bias,
                        int M, int N, int K) {
  __shared__ __align__(16) unsigned short As[128 * 64];
  __shared__ __align__(16) unsigned short Bs[128 * 64];
  const int tid  = threadIdx.x;
  const int lane = tid & 63;
  const int w    = tid >> 6;      // wave 0..3
  const int wr   = w >> 1, wc = w & 1;
  const int l16  = lane & 15, lh = lane >> 4;
  const long arow0 = (long)blockIdx.x * 128;
  const long bcol0 = (long)blockIdx.y * 128;

  f32x4 acc[4][4];
#pragma unroll
  for (int mi = 0; mi < 4; ++mi)
#pragma unroll
    for (int ni = 0; ni < 4; ++ni) acc[mi][ni] = f32x4{0.f, 0.f, 0.f, 0.f};

  for (int k0 = 0; k0 < K; k0 += 64) {
    // stage A,B tiles: 16KB each; per wave 4 sections of 1KB (8 rows x 64 cols)
#pragma unroll
    for (int i = 0; i < 4; ++i) {
      int sec = i * 4 + w;                 // 0..15, wave-uniform
      int row = sec * 8 + (lane >> 3);     // per-lane row
      int col = (lane & 7) * 8;            // element col (16B chunk)
      const unsigned short* ga = A + (arow0 + row) * (long)K + k0 + col;
      const unsigned short* gb = W + (bcol0 + row) * (long)K + k0 + col;
      __builtin_amdgcn_global_load_lds(
          (const __attribute__((address_space(1))) void*)ga,
          (__attribute__((address_space(3))) void*)&As[sec * 512], 16, 0, 0);
      __builtin_amdgcn_global_load_lds(
          (const __attribute__((address_space(1))) void*)gb,
          (__attribute__((address_space(3))) void*)&Bs[sec * 512], 16, 0, 0);
    }
    __syncthreads();
#pragma unroll
    for (int kk = 0; kk < 2; ++kk) {
      bf16x8 af[4], bf[4];
#pragma unroll
      for (int mi = 0; mi < 4; ++mi)
        af[mi] = __builtin_bit_cast(bf16x8,
            *(const s16x8*)&As[(wr * 64 + mi * 16 + l16) * 64 + kk * 32 + lh * 8]);
#pragma unroll
      for (int ni = 0; ni < 4; ++ni)
        bf[ni] = __builtin_bit_cast(bf16x8,
            *(const s16x8*)&Bs[(wc * 64 + ni * 16 + l16) * 64 + kk * 32 + lh * 8]);
#pragma unroll
      for (int mi = 0; mi < 4; ++mi)
#pragma unroll
        for (int ni = 0; ni < 4; ++ni)
          acc[mi][ni] = __builtin_amdgcn_mfma_f32_16x16x32_bf16(af[mi], bf[ni], acc[mi][ni], 0, 0, 0);
    }
    __syncthreads();
  }

#pragma unroll
  for (int mi = 0; mi < 4; ++mi)
#pragma unroll
    for (int ni = 0; ni < 4; ++ni)
#pragma unroll
      for (int j = 0; j < 4; ++j) {
        long row = arow0 + wr * 64 + mi * 16 + lh * 4 + j;
        long col = bcol0 + wc * 64 + ni * 16 + l16;
        float v = acc[mi][ni][j];
        if (HAS_BIAS) v += bias[col];
        if (BF16_OUT) ((unsigned short*)Cv)[row * N + col] = f2b(v);
        else          ((float*)Cv)[row * N + col] = v;
      }
}

// ---------------- elementwise / prep kernels ----------------
__global__ void cast_x_kernel(const float* __restrict__ x, unsigned short* __restrict__ xb) {
  long i = ((long)blockIdx.x * 256 + threadIdx.x) * 4;
  float4 v = *reinterpret_cast<const float4*>(x + i);
  ushort4 o = {f2b(v.x), f2b(v.y), f2b(v.z), f2b(v.w)};
  *reinterpret_cast<ushort4*>(xb + i) = o;
}

__global__ void prep_wall_kernel(const float* __restrict__ Wr1, const float* __restrict__ Wr2,
                                 const float* __restrict__ Wr3, const float* __restrict__ Wl,
                                 unsigned short* __restrict__ Wall) {
  int idx = blockIdx.x * 256 + threadIdx.x;   // one thread per 4 elems
  int base = idx * 4;
  int n = base / DMODEL, k = base % DMODEL;
  const float* src = (n < 256)  ? Wr1 + (long)n * DMODEL
                   : (n < 512)  ? Wr2 + (long)(n - 256) * DMODEL
                   : (n < 768)  ? Wr3 + (long)(n - 512) * DMODEL
                                : Wl  + (long)(n - 768) * DMODEL;
  float4 v = *reinterpret_cast<const float4*>(src + k);
  ushort4 o = {f2b(v.x), f2b(v.y), f2b(v.z), f2b(v.w)};
  *reinterpret_cast<ushort4*>(Wall + base) = o;
}

// Wg[n=h*256+b][a] = sum_d Wq[h*64+d][a]*Wk[h*64+d][b];  dvec[n] = sum_d bq[h*64+d]*Wk[h*64+d][b]
__global__ void prep_G_kernel(const float* __restrict__ Wq, const float* __restrict__ Wk,
                              const float* __restrict__ bq, unsigned short* __restrict__ Wg,
                              float* __restrict__ dvec) {
  int idx = blockIdx.x * 256 + threadIdx.x;
  int n = idx >> 8, a = idx & 255;
  int h = n >> 8, b = n & 255;
  const float* wq = Wq + (long)(h * 64) * 256 + a;
  const float* wk = Wk + (long)(h * 64) * 256 + b;
  float s = 0.f;
  for (int d = 0; d < 64; ++d) s += wq[d * 256] * wk[d * 256];
  Wg[(long)n * 256 + a] = f2b(s);
  if (a == 0) {
    float t = 0.f;
    const float* bqh = bq + h * 64;
    for (int d = 0; d < 64; ++d) t += bqh[d] * wk[d * 256];
    dvec[n] = t;
  }
}

// Wp[m][n=h*256+b] = sum_d Wo[m][h*64+d]*Wv[h*64+d][b];  bo2[m] = bo[m] + sum_j Wo[m][j]*bv[j]
__global__ void prep_P_kernel(const float* __restrict__ Wo, const float* __restrict__ Wv,
                              const float* __restrict__ bv, const float* __restrict__ bo,
                              unsigned short* __restrict__ Wp, float* __restrict__ bo2) {
  int idx = blockIdx.x * 256 + threadIdx.x;
  int m = idx >> 10, n = idx & 1023;
  int h = n >> 8, b = n & 255;
  const float* wo = Wo + (long)m * 256 + h * 64;
  const float* wv = Wv + (long)(h * 64) * 256 + b;
  float s = 0.f;
  for (int d = 0; d < 64; ++d) s += wo[d] * wv[d * 256];
  Wp[(long)m * 1024 + n] = f2b(s);
  if (n == 0) {
    float t = bo[m];
    const float* wor = Wo + (long)m * 256;
    for (int j = 0; j < 256; ++j) t += wor[j] * bv[j];
    bo2[m] = t;
  }
}

// per-token: 3x L2norm + (bias+LN+L2norm) + q=mean; in-place H -> feats
__global__ void norm_kernel(unsigned short* __restrict__ H, unsigned short* __restrict__ q,
                            const float* __restrict__ bl, const float* __restrict__ lng,
                            const float* __restrict__ lnb) {
  int token = blockIdx.x * 4 + (threadIdx.x >> 6);
  int lane = threadIdx.x & 63;
  unsigned short* row = H + (long)token * 1024;
  int b0 = lane * 4;
  float h[4][4];
#pragma unroll
  for (int s = 0; s < 4; ++s) {
    ushort4 v = *reinterpret_cast<const ushort4*>(row + s * 256 + b0);
    h[s][0] = b2f(v.x); h[s][1] = b2f(v.y); h[s][2] = b2f(v.z); h[s][3] = b2f(v.w);
  }
  float4 blv = *reinterpret_cast<const float4*>(bl + b0);
  h[3][0] += blv.x; h[3][1] += blv.y; h[3][2] += blv.z; h[3][3] += blv.w;

  float ss0 = 0, ss1 = 0, ss2 = 0, s3 = 0, ss3 = 0;
#pragma unroll
  for (int j = 0; j < 4; ++j) {
    ss0 += h[0][j] * h[0][j];
    ss1 += h[1][j] * h[1][j];
    ss2 += h[2][j] * h[2][j];
    s3  += h[3][j];
    ss3 += h[3][j] * h[3][j];
  }
  ss0 = wsum(ss0); ss1 = wsum(ss1); ss2 = wsum(ss2); s3 = wsum(s3); ss3 = wsum(ss3);
  float i0 = 1.f / fmaxf(sqrtf(ss0), 1e-12f);
  float i1 = 1.f / fmaxf(sqrtf(ss1), 1e-12f);
  float i2 = 1.f / fmaxf(sqrtf(ss2), 1e-12f);
  float mu = s3 * (1.f / 256.f);
  float var = ss3 * (1.f / 256.f) - mu * mu;
  float is = rsqrtf(var + 1e-5f);
  float4 gv = *reinterpret_cast<const float4*>(lng + b0);
  float4 bv = *reinterpret_cast<const float4*>(lnb + b0);
  float hn[4];
  hn[0] = (h[3][0] - mu) * is * gv.x + bv.x;
  hn[1] = (h[3][1] - mu) * is * gv.y + bv.y;
  hn[2] = (h[3][2] - mu) * is * gv.z + bv.z;
  hn[3] = (h[3][3] - mu) * is * gv.w + bv.w;
  float ssn = hn[0]*hn[0] + hn[1]*hn[1] + hn[2]*hn[2] + hn[3]*hn[3];
  ssn = wsum(ssn);
  float i3 = 1.f / fmaxf(sqrtf(ssn), 1e-12f);

  float f0[4], f1[4], f2[4], f3[4], qv[4];
#pragma unroll
  for (int j = 0; j < 4; ++j) {
    f0[j] = h[0][j] * i0; f1[j] = h[1][j] * i1; f2[j] = h[2][j] * i2; f3[j] = hn[j] * i3;
    qv[j] = 0.25f * (f0[j] + f1[j] + f2[j] + f3[j]);
  }
  ushort4 o0 = {f2b(f0[0]), f2b(f0[1]), f2b(f0[2]), f2b(f0[3])};
  ushort4 o1 = {f2b(f1[0]), f2b(f1[1]), f2b(f1[2]), f2b(f1[3])};
  ushort4 o2 = {f2b(f2[0]), f2b(f2[1]), f2b(f2[2]), f2b(f2[3])};
  ushort4 o3 = {f2b(f3[0]), f2b(f3[1]), f2b(f3[2]), f2b(f3[3])};
  ushort4 oq = {f2b(qv[0]), f2b(qv[1]), f2b(qv[2]), f2b(qv[3])};
  *reinterpret_cast<ushort4*>(row + 0 * 256 + b0) = o0;
  *reinterpret_cast<ushort4*>(row + 1 * 256 + b0) = o1;
  *reinterpret_cast<ushort4*>(row + 2 * 256 + b0) = o2;
  *reinterpret_cast<ushort4*>(row + 3 * 256 + b0) = o3;
  *reinterpret_cast<ushort4*>(q + (long)token * 256 + b0) = oq;
}

// per-token: scores from U,feats; softmax over 4 branches; g_h = sum_k a[h,k] f_k; in-place U -> g
__global__ void attn_kernel(unsigned short* __restrict__ U, const unsigned short* __restrict__ F) {
  int token = blockIdx.x * 4 + (threadIdx.x >> 6);
  int lane = threadIdx.x & 63;
  unsigned short* urow = U + (long)token * 1024;
  const unsigned short* frow = F + (long)token * 1024;
  int b0 = lane * 4;
  float u[4][4], f[4][4];
#pragma unroll
  for (int s = 0; s < 4; ++s) {
    ushort4 uv = *reinterpret_cast<const ushort4*>(urow + s * 256 + b0);
    ushort4 fv = *reinterpret_cast<const ushort4*>(frow + s * 256 + b0);
    u[s][0] = b2f(uv.x); u[s][1] = b2f(uv.y); u[s][2] = b2f(uv.z); u[s][3] = b2f(uv.w);
    f[s][0] = b2f(fv.x); f[s][1] = b2f(fv.y); f[s][2] = b2f(fv.z); f[s][3] = b2f(fv.w);
  }
  float sc[4][4];
#pragma unroll
  for (int h = 0; h < 4; ++h)
#pragma unroll
    for (int k = 0; k < 4; ++k) {
      float s = 0.f;
#pragma unroll
      for (int j = 0; j < 4; ++j) s += u[h][j] * f[k][j];
      sc[h][k] = wsum(s);
    }
  float g[4][4];
#pragma unroll
  for (int h = 0; h < 4; ++h) {
    float m = fmaxf(fmaxf(sc[h][0], sc[h][1]), fmaxf(sc[h][2], sc[h][3]));
    float e0 = __expf((sc[h][0] - m) * 0.125f);
    float e1 = __expf((sc[h][1] - m) * 0.125f);
    float e2 = __expf((sc[h][2] - m) * 0.125f);
    float e3 = __expf((sc[h][3] - m) * 0.125f);
    float inv = 1.f / (e0 + e1 + e2 + e3);
#pragma unroll
    for (int j = 0; j < 4; ++j)
      g[h][j] = (e0 * f[0][j] + e1 * f[1][j] + e2 * f[2][j] + e3 * f[3][j]) * inv;
  }
#pragma unroll
  for (int h = 0; h < 4; ++h) {
    ushort4 o = {f2b(g[h][0]), f2b(g[h][1]), f2b(g[h][2]), f2b(g[h][3])};
    *reinterpret_cast<ushort4*>(urow + h * 256 + b0) = o;
  }
}

__global__ void l2_out_kernel(const float* __restrict__ in, float* __restrict__ out) {
  int token = blockIdx.x * 4 + (threadIdx.x >> 6);
  int lane = threadIdx.x & 63;
  float4 v = reinterpret_cast<const float4*>(in + (long)token * 256)[lane];
  float ss = wsum(v.x * v.x + v.y * v.y + v.z * v.z + v.w * v.w);
  float inv = 1.f / fmaxf(sqrtf(ss), 1e-12f);
  float4 o = {v.x * inv, v.y * inv, v.z * inv, v.w * inv};
  reinterpret_cast<float4*>(out + (long)token * 256)[lane] = o;
}

extern "C" void kernel_launch(void* const* d_in, const int* in_sizes, int n_in,
                              void* d_out, int out_size, void* d_ws, size_t ws_size,
                              hipStream_t stream) {
  const float* x   = (const float*)d_in[0];
  const float* Wr1 = (const float*)d_in[1];
  const float* Wr2 = (const float*)d_in[2];
  const float* Wr3 = (const float*)d_in[3];
  const float* Wl  = (const float*)d_in[4];
  const float* bl  = (const float*)d_in[5];
  const float* lng = (const float*)d_in[6];
  const float* lnb = (const float*)d_in[7];
  const float* Wq  = (const float*)d_in[8];
  const float* bq  = (const float*)d_in[9];
  const float* Wk  = (const float*)d_in[10];
  const float* Wv  = (const float*)d_in[12];
  const float* bv  = (const float*)d_in[13];
  const float* Wo  = (const float*)d_in[14];
  const float* bo  = (const float*)d_in[15];

  char* ws = (char*)d_ws;
  size_t off = 0;
  auto alloc = [&](size_t bytes) -> void* {
    void* p = ws + off;
    off += (bytes + 255) & ~(size_t)255;
    return p;
  };
  unsigned short* xbf  = (unsigned short*)alloc((size_t)TOK * DMODEL * 2);  // 100.7 MB
  unsigned short* H    = (unsigned short*)alloc((size_t)TOK * 1024 * 2);    // 134.2 MB (-> feats)
  unsigned short* qb   = (unsigned short*)alloc((size_t)TOK * 256 * 2);     // 33.6 MB
  unsigned short* U    = (unsigned short*)alloc((size_t)TOK * 1024 * 2);    // 134.2 MB (-> g)
  unsigned short* Wall = (unsigned short*)alloc((size_t)1024 * DMODEL * 2);
  unsigned short* Wg   = (unsigned short*)alloc((size_t)1024 * 256 * 2);
  unsigned short* Wp   = (unsigned short*)alloc((size_t)256 * 1024 * 2);
  float* dvec = (float*)alloc(1024 * 4);
  float* bo2  = (float*)alloc(256 * 4);
  float* outpre = (float*)xbf;  // reuse: xbf dead after first GEMM chain stage

  cast_x_kernel<<<(TOK * DMODEL) / 1024, 256, 0, stream>>>(x, xbf);
  prep_wall_kernel<<<(1024 * DMODEL) / 1024, 256, 0, stream>>>(Wr1, Wr2, Wr3, Wl, Wall);
  prep_G_kernel<<<1024, 256, 0, stream>>>(Wq, Wk, (const float*)d_in[9], Wg, dvec);
  prep_P_kernel<<<1024, 256, 0, stream>>>(Wo, Wv, bv, bo, Wp, bo2);

  // H = X @ Wall^T   [65536,1024], K=768
  gemm_bt<true, false><<<dim3(512, 8), 256, 0, stream>>>(xbf, Wall, H, nullptr, TOK, 1024, DMODEL);
  // normalize branches, build feats (in place) + q
  norm_kernel<<<TOK / 4, 256, 0, stream>>>(H, qb, bl, lng, lnb);
  // U = q @ Wg^T + dvec   [65536,1024], K=256
  gemm_bt<true, true><<<dim3(512, 8), 256, 0, stream>>>(qb, Wg, U, dvec, TOK, 1024, 256);
  // attention mix: U(in)=U, F=feats(H); writes g in place of U
  attn_kernel<<<TOK / 4, 256, 0, stream>>>(U, H);
  // outpre = g @ Wp^T + bo2   [65536,256], K=1024
  gemm_bt<false, true><<<dim3(512, 2), 256, 0, stream>>>(U, Wp, outpre, bo2, TOK, 256, 1024);
  // final row L2 norm -> d_out
  l2_out_kernel<<<TOK / 4, 256, 0, stream>>>(outpre, (float*)d_out);

  (void)in_sizes; (void)n_in; (void)out_size; (void)ws_size; (void)bq;
}